// Round 5
// baseline (295.718 us; speedup 1.0000x reference)
//
#include <hip/hip_runtime.h>
#include <stdint.h>

#define N_Q   16384
#define N_CLS 1024
#define DIM_H 2048
#define NT    (DIM_H / 64)                    // 32 k-tiles
#define QBLK  ((N_Q * DIM_H) / (256 * 8))     // 16384 blocks for Q cvt
#define CBLK  ((N_CLS * DIM_H) / (256 * 8))   // 1024 blocks for cls cvt

typedef __bf16 bf16x8 __attribute__((ext_vector_type(8)));
typedef float  f32x4  __attribute__((ext_vector_type(4)));

// pack two fp32 -> two bf16 (round-to-nearest ties-away): 2 adds + 1 merge
__device__ __forceinline__ uint32_t pk2(float a, float b) {
    uint32_t ua = __float_as_uint(a) + 0x8000u;
    uint32_t ub = __float_as_uint(b) + 0x8000u;
    return (ua >> 16) | (ub & 0xFFFF0000u);
}

// direct-to-LDS 16B staging; HW dest = wave-uniform base + lane*16
__device__ __forceinline__ void load_lds16(const __bf16* g, __bf16* l) {
    __builtin_amdgcn_global_load_lds(
        (const __attribute__((address_space(1))) uint32_t*)g,
        (__attribute__((address_space(3))) uint32_t*)l, 16, 0, 0);
}

// single prepass: Q fp32->bf16 (blocks 0..QBLK-1), cls fp32*M->bf16 (rest)
__global__ void prep_kernel(const float* __restrict__ q,
                            const float* __restrict__ cls,
                            const float* __restrict__ M,
                            uint16_t* __restrict__ qo,
                            uint16_t* __restrict__ co) {
    const int bid = blockIdx.x;
    if (bid < QBLK) {
        size_t e = ((size_t)bid * 256 + threadIdx.x) * 8;
        float4 a = *(const float4*)(q + e);
        float4 b = *(const float4*)(q + e + 4);
        *(uint4*)(qo + e) = make_uint4(pk2(a.x, a.y), pk2(a.z, a.w),
                                       pk2(b.x, b.y), pk2(b.z, b.w));
    } else {
        size_t e = ((size_t)(bid - QBLK) * 256 + threadIdx.x) * 8;
        float4 c0 = *(const float4*)(cls + e);
        float4 c1 = *(const float4*)(cls + e + 4);
        const float* mp = M + (e & (DIM_H - 1));
        float4 m0 = *(const float4*)mp;
        float4 m1 = *(const float4*)(mp + 4);
        *(uint4*)(co + e) = make_uint4(pk2(c0.x * m0.x, c0.y * m0.y),
                                       pk2(c0.z * m0.z, c0.w * m0.w),
                                       pk2(c1.x * m1.x, c1.y * m1.y),
                                       pk2(c1.z * m1.z, c1.w * m1.w));
    }
}

// 256x256 tile, BK=64, 8 waves (2M x 4N), per-wave 128x64 output.
// Grid = 256 blocks = 1 block/CU (8 waves, 128KB LDS).
// R4 staging kept: per K-tile, 8-gload burst into slot s^1, vmcnt(8) = tile t
// landed while t+1's 8 stay in flight (never drained in main loop).
// NEW (R5): compute phase-split per m201 8-phase template -- 4 phases/tile,
// phase = (qm half of wave's 128 M-rows, ks half of K=64):
//   { ds_read 4-8 x b128 ; s_barrier ; setprio(1) ; 16 MFMA ; setprio(0) ;
//     s_barrier }
// B-frags per ks read once, held across both qm phases (LDS traffic
// unchanged: 24 b128/wave/tile). Raw asm barriers ("memory" clobber) fence
// reads into their phase; compiler still emits fine-grained lgkmcnt.
// LDS XOR-8 chunk swizzle (0 conflicts measured): chunk(row r, pos p) holds
// k-chunk p^(r&7); fragment read pos x = ((ks*4+fq)^(frow&7))*8.
__global__ __launch_bounds__(512, 2)
void gemm_kernel(const uint16_t* __restrict__ Qp,   // (N,H) bf16
                 const uint16_t* __restrict__ Bp,   // (C,H) bf16 pre-scaled
                 float* __restrict__ Out) {         // (N,C) fp32
    __shared__ __align__(16) __bf16 As[2][256 * 64];
    __shared__ __align__(16) __bf16 Bs[2][256 * 64];

    const int tid  = threadIdx.x;
    const int lane = tid & 63;
    const int wave = tid >> 6;

    const int b    = blockIdx.x;            // 0..255
    const int xcd  = b & 7;
    const int t0   = b >> 3;                // 0..31
    const int row0 = (xcd * 8 + (t0 & 7)) * 256;    // query rows (64 panels)
    const int col0 = (t0 >> 3) * 256;               // class cols (4 panels)

    const int wm   = (wave >> 2) * 128;     // 2 waves in M
    const int wn   = (wave & 3) * 64;       // 4 waves in N
    const int frow = lane & 15;
    const int fq   = lane >> 4;

    const __bf16* Q = (const __bf16*)Qp;
    const __bf16* B = (const __bf16*)Bp;

    f32x4 acc[8][4] = {};

    // stage K-tile kt (A: 256x64, B: 256x64) into slot s: 8 gloads/thread.
    auto stage = [&](int kt, int s) {
#pragma unroll
        for (int i = 0; i < 4; ++i) {
            const int cb = i * 512 + wave * 64;
            const int c  = cb + lane;
            const int r  = c >> 3;
            const int g  = (c & 7) ^ (r & 7);
            load_lds16(Q + (size_t)(row0 + r) * DIM_H + kt * 64 + g * 8,
                       &As[s][cb * 8]);
            load_lds16(B + (size_t)(col0 + r) * DIM_H + kt * 64 + g * 8,
                       &Bs[s][cb * 8]);
        }
    };

    stage(0, 0);   // prologue: tile 0 -> slot 0 (8 loads in flight)

    for (int t = 0; t < NT; ++t) {
        const int s = t & 1;

        if (t + 1 < NT) {
            stage(t + 1, s ^ 1);                     // 8 more loads in flight
            asm volatile("s_waitcnt vmcnt(8)" ::: "memory");  // tile t landed
        } else {
            asm volatile("s_waitcnt vmcnt(0)" ::: "memory");
        }
        asm volatile("s_barrier" ::: "memory");      // slot s ready (all waves)

        bf16x8 af[4], bfr[4];
#pragma unroll
        for (int ks = 0; ks < 2; ++ks) {
            const int x = ((ks * 4 + fq) ^ (frow & 7)) * 8;

            // ---- phase (qm=0, ks): read B(ks) + A(qm0,ks) ----
#pragma unroll
            for (int u = 0; u < 4; ++u)
                bfr[u] = *(const bf16x8*)&Bs[s][(wn + u * 16 + frow) * 64 + x];
#pragma unroll
            for (int i = 0; i < 4; ++i)
                af[i] = *(const bf16x8*)&As[s][(wm + i * 16 + frow) * 64 + x];
            asm volatile("s_barrier" ::: "memory");
            __builtin_amdgcn_s_setprio(1);
#pragma unroll
            for (int i = 0; i < 4; ++i)
#pragma unroll
                for (int u = 0; u < 4; ++u)
                    acc[i][u] = __builtin_amdgcn_mfma_f32_16x16x32_bf16(
                        af[i], bfr[u], acc[i][u], 0, 0, 0);
            __builtin_amdgcn_s_setprio(0);
            asm volatile("s_barrier" ::: "memory");

            // ---- phase (qm=1, ks): read A(qm1,ks), reuse B(ks) ----
#pragma unroll
            for (int i = 0; i < 4; ++i)
                af[i] = *(const bf16x8*)&As[s][(wm + 64 + i * 16 + frow) * 64 + x];
            asm volatile("s_barrier" ::: "memory");
            __builtin_amdgcn_s_setprio(1);
#pragma unroll
            for (int i = 0; i < 4; ++i)
#pragma unroll
                for (int u = 0; u < 4; ++u)
                    acc[4 + i][u] = __builtin_amdgcn_mfma_f32_16x16x32_bf16(
                        af[i], bfr[u], acc[4 + i][u], 0, 0, 0);
            __builtin_amdgcn_s_setprio(0);
            asm volatile("s_barrier" ::: "memory");  // ks1/qm1: end-of-tile
        }
    }

    // ---- epilogue: C/D layout col=lane&15, row=(lane>>4)*4+reg; fp32 out ----
#pragma unroll
    for (int tt = 0; tt < 8; ++tt) {
#pragma unroll
        for (int u = 0; u < 4; ++u) {
            const int row = row0 + wm + tt * 16 + fq * 4;
            const int col = col0 + wn + u * 16 + frow;
#pragma unroll
            for (int r = 0; r < 4; ++r)
                Out[(size_t)(row + r) * N_CLS + col] = acc[tt][u][r];
        }
    }
}

// correctness fallback (fp32 end-to-end) if workspace is too small
__global__ void naive_kernel(const float* __restrict__ Q,
                             const float* __restrict__ C,
                             const float* __restrict__ M,
                             float* __restrict__ Out) {
    size_t idx = (size_t)blockIdx.x * 256 + threadIdx.x;
    int n = (int)(idx >> 10), c = (int)(idx & (N_CLS - 1));
    float s = 0.f;
    for (int h = 0; h < DIM_H; ++h)
        s += Q[(size_t)n * DIM_H + h] * C[(size_t)c * DIM_H + h] * M[h];
    Out[idx] = s;
}

extern "C" void kernel_launch(void* const* d_in, const int* in_sizes, int n_in,
                              void* d_out, int out_size, void* d_ws, size_t ws_size,
                              hipStream_t stream) {
    const float* cls = (const float*)d_in[0];   // (C,H)
    const float* q   = (const float*)d_in[1];   // (N,H)
    const float* M   = (const float*)d_in[2];   // (H,1)
    for (int i = 0; i < n_in; ++i) {
        if      (in_sizes[i] == N_CLS * DIM_H) cls = (const float*)d_in[i];
        else if (in_sizes[i] == N_Q * DIM_H)   q   = (const float*)d_in[i];
        else if (in_sizes[i] == DIM_H)         M   = (const float*)d_in[i];
    }
    float* out = (float*)d_out;

    const size_t cls_bytes = (size_t)N_CLS * DIM_H * sizeof(uint16_t);  //  4 MB
    const size_t q_bytes   = (size_t)N_Q * DIM_H * sizeof(uint16_t);    // 67 MB
    if (ws_size >= cls_bytes + q_bytes) {
        uint16_t* cls_bf = (uint16_t*)d_ws;
        uint16_t* q_bf   = (uint16_t*)((char*)d_ws + cls_bytes);
        prep_kernel<<<QBLK + CBLK, 256, 0, stream>>>(q, cls, M, q_bf, cls_bf);
        gemm_kernel<<<(N_Q / 256) * (N_CLS / 256), 512, 0, stream>>>(q_bf, cls_bf, out);
    } else {
        naive_kernel<<<(unsigned)(((size_t)N_Q * N_CLS) / 256), 256, 0, stream>>>(q, cls, M, out);
    }
}

// Round 6
// 282.168 us; speedup vs baseline: 1.0480x; 1.0480x over previous
//
#include <hip/hip_runtime.h>
#include <stdint.h>

#define N_Q   16384
#define N_CLS 1024
#define DIM_H 2048
#define NT    (DIM_H / 64)                    // 32 k-tiles
#define QBLK  ((N_Q * DIM_H) / (256 * 8))     // 16384 blocks for Q cvt
#define CBLK  ((N_CLS * DIM_H) / (256 * 8))   // 1024 blocks for cls cvt

typedef __bf16 bf16x8 __attribute__((ext_vector_type(8)));
typedef float  f32x4  __attribute__((ext_vector_type(4)));

// pack two fp32 -> two bf16 (round-to-nearest ties-away): 2 adds + 1 merge
__device__ __forceinline__ uint32_t pk2(float a, float b) {
    uint32_t ua = __float_as_uint(a) + 0x8000u;
    uint32_t ub = __float_as_uint(b) + 0x8000u;
    return (ua >> 16) | (ub & 0xFFFF0000u);
}

// direct-to-LDS 16B staging; HW dest = wave-uniform base + lane*16
__device__ __forceinline__ void load_lds16(const __bf16* g, __bf16* l) {
    __builtin_amdgcn_global_load_lds(
        (const __attribute__((address_space(1))) uint32_t*)g,
        (__attribute__((address_space(3))) uint32_t*)l, 16, 0, 0);
}

// single prepass: Q fp32->bf16 (blocks 0..QBLK-1), cls fp32*M->bf16 (rest)
__global__ void prep_kernel(const float* __restrict__ q,
                            const float* __restrict__ cls,
                            const float* __restrict__ M,
                            uint16_t* __restrict__ qo,
                            uint16_t* __restrict__ co) {
    const int bid = blockIdx.x;
    if (bid < QBLK) {
        size_t e = ((size_t)bid * 256 + threadIdx.x) * 8;
        float4 a = *(const float4*)(q + e);
        float4 b = *(const float4*)(q + e + 4);
        *(uint4*)(qo + e) = make_uint4(pk2(a.x, a.y), pk2(a.z, a.w),
                                       pk2(b.x, b.y), pk2(b.z, b.w));
    } else {
        size_t e = ((size_t)(bid - QBLK) * 256 + threadIdx.x) * 8;
        float4 c0 = *(const float4*)(cls + e);
        float4 c1 = *(const float4*)(cls + e + 4);
        const float* mp = M + (e & (DIM_H - 1));
        float4 m0 = *(const float4*)mp;
        float4 m1 = *(const float4*)(mp + 4);
        *(uint4*)(co + e) = make_uint4(pk2(c0.x * m0.x, c0.y * m0.y),
                                       pk2(c0.z * m0.z, c0.w * m0.w),
                                       pk2(c1.x * m1.x, c1.y * m1.y),
                                       pk2(c1.z * m1.z, c1.w * m1.w));
    }
}

// 256x256 tile, BK=64, 8 waves (2M x 4N), per-wave 128x64 output.
// Grid = 256 blocks = 1 block/CU (8 waves, 128KB LDS).
// R4 structure kept verbatim: per K-tile, 8-gload burst into slot s^1,
// vmcnt(8) = tile t landed while t+1's 8 stay in flight; 2 barriers/tile.
// NEW (R6): in-register ks-pipeline. ALL 24 fragment ds_read_b128 (ks0 set
// af0/bf0 + ks1 set af1/bf1) are issued before any MFMA; sched_barrier(0)
// pins them there. Compiler's fine-grained lgkmcnt lets the 32 ks0 MFMAs
// execute while ks1's 12 reads are still in flight -> LDS-read and MFMA
// pipes overlap (R4 serialized them: 5925 cyc/tile = read-sum + mfma-sum).
// LDS XOR-8 chunk swizzle (0 conflicts measured): chunk(row r, pos p) holds
// k-chunk p^(r&7); fragment read pos x = ((ks*4+fq)^(frow&7))*8.
__global__ __launch_bounds__(512, 2)
void gemm_kernel(const uint16_t* __restrict__ Qp,   // (N,H) bf16
                 const uint16_t* __restrict__ Bp,   // (C,H) bf16 pre-scaled
                 float* __restrict__ Out) {         // (N,C) fp32
    __shared__ __align__(16) __bf16 As[2][256 * 64];
    __shared__ __align__(16) __bf16 Bs[2][256 * 64];

    const int tid  = threadIdx.x;
    const int lane = tid & 63;
    const int wave = tid >> 6;

    const int b    = blockIdx.x;            // 0..255
    const int xcd  = b & 7;
    const int t0   = b >> 3;                // 0..31
    const int row0 = (xcd * 8 + (t0 & 7)) * 256;    // query rows (64 panels)
    const int col0 = (t0 >> 3) * 256;               // class cols (4 panels)

    const int wm   = (wave >> 2) * 128;     // 2 waves in M
    const int wn   = (wave & 3) * 64;       // 4 waves in N
    const int frow = lane & 15;
    const int fq   = lane >> 4;

    const __bf16* Q = (const __bf16*)Qp;
    const __bf16* B = (const __bf16*)Bp;

    f32x4 acc[8][4] = {};

    // stage K-tile kt (A: 256x64, B: 256x64) into slot s: 8 gloads/thread.
    auto stage = [&](int kt, int s) {
#pragma unroll
        for (int i = 0; i < 4; ++i) {
            const int cb = i * 512 + wave * 64;
            const int c  = cb + lane;
            const int r  = c >> 3;
            const int g  = (c & 7) ^ (r & 7);
            load_lds16(Q + (size_t)(row0 + r) * DIM_H + kt * 64 + g * 8,
                       &As[s][cb * 8]);
            load_lds16(B + (size_t)(col0 + r) * DIM_H + kt * 64 + g * 8,
                       &Bs[s][cb * 8]);
        }
    };

    stage(0, 0);   // prologue: tile 0 -> slot 0 (8 loads in flight)

    const int x0 = ((0 * 4 + fq) ^ (frow & 7)) * 8;   // ks0 swizzled k-pos
    const int x1 = ((1 * 4 + fq) ^ (frow & 7)) * 8;   // ks1 swizzled k-pos

    for (int t = 0; t < NT; ++t) {
        const int s = t & 1;

        if (t + 1 < NT) {
            stage(t + 1, s ^ 1);                     // 8 more loads in flight
            asm volatile("s_waitcnt vmcnt(8)" ::: "memory");  // tile t landed
        } else {
            asm volatile("s_waitcnt vmcnt(0)" ::: "memory");
        }
        __builtin_amdgcn_s_barrier();                // slot s ready (all waves)

        // ---- issue ALL fragment reads first (ks0 then ks1) ----
        bf16x8 af0[8], bf0[4], af1[8], bf1[4];
#pragma unroll
        for (int tt = 0; tt < 8; ++tt)
            af0[tt] = *(const bf16x8*)&As[s][(wm + tt * 16 + frow) * 64 + x0];
#pragma unroll
        for (int u = 0; u < 4; ++u)
            bf0[u] = *(const bf16x8*)&Bs[s][(wn + u * 16 + frow) * 64 + x0];
#pragma unroll
        for (int tt = 0; tt < 8; ++tt)
            af1[tt] = *(const bf16x8*)&As[s][(wm + tt * 16 + frow) * 64 + x1];
#pragma unroll
        for (int u = 0; u < 4; ++u)
            bf1[u] = *(const bf16x8*)&Bs[s][(wn + u * 16 + frow) * 64 + x1];
        __builtin_amdgcn_sched_barrier(0);   // pin reads above the MFMAs

        // ---- ks0 MFMAs run while ks1 reads are still in flight ----
#pragma unroll
        for (int tt = 0; tt < 8; ++tt)
#pragma unroll
            for (int u = 0; u < 4; ++u)
                acc[tt][u] = __builtin_amdgcn_mfma_f32_16x16x32_bf16(
                    af0[tt], bf0[u], acc[tt][u], 0, 0, 0);
#pragma unroll
        for (int tt = 0; tt < 8; ++tt)
#pragma unroll
            for (int u = 0; u < 4; ++u)
                acc[tt][u] = __builtin_amdgcn_mfma_f32_16x16x32_bf16(
                    af1[tt], bf1[u], acc[tt][u], 0, 0, 0);

        if (t + 1 < NT)
            __builtin_amdgcn_s_barrier();            // reads done; slot s^1
    }                                                //  overwrite safe next it

    // ---- epilogue: C/D layout col=lane&15, row=(lane>>4)*4+reg; fp32 out ----
#pragma unroll
    for (int tt = 0; tt < 8; ++tt) {
#pragma unroll
        for (int u = 0; u < 4; ++u) {
            const int row = row0 + wm + tt * 16 + fq * 4;
            const int col = col0 + wn + u * 16 + frow;
#pragma unroll
            for (int r = 0; r < 4; ++r)
                Out[(size_t)(row + r) * N_CLS + col] = acc[tt][u][r];
        }
    }
}

// correctness fallback (fp32 end-to-end) if workspace is too small
__global__ void naive_kernel(const float* __restrict__ Q,
                             const float* __restrict__ C,
                             const float* __restrict__ M,
                             float* __restrict__ Out) {
    size_t idx = (size_t)blockIdx.x * 256 + threadIdx.x;
    int n = (int)(idx >> 10), c = (int)(idx & (N_CLS - 1));
    float s = 0.f;
    for (int h = 0; h < DIM_H; ++h)
        s += Q[(size_t)n * DIM_H + h] * C[(size_t)c * DIM_H + h] * M[h];
    Out[idx] = s;
}

extern "C" void kernel_launch(void* const* d_in, const int* in_sizes, int n_in,
                              void* d_out, int out_size, void* d_ws, size_t ws_size,
                              hipStream_t stream) {
    const float* cls = (const float*)d_in[0];   // (C,H)
    const float* q   = (const float*)d_in[1];   // (N,H)
    const float* M   = (const float*)d_in[2];   // (H,1)
    for (int i = 0; i < n_in; ++i) {
        if      (in_sizes[i] == N_CLS * DIM_H) cls = (const float*)d_in[i];
        else if (in_sizes[i] == N_Q * DIM_H)   q   = (const float*)d_in[i];
        else if (in_sizes[i] == DIM_H)         M   = (const float*)d_in[i];
    }
    float* out = (float*)d_out;

    const size_t cls_bytes = (size_t)N_CLS * DIM_H * sizeof(uint16_t);  //  4 MB
    const size_t q_bytes   = (size_t)N_Q * DIM_H * sizeof(uint16_t);    // 67 MB
    if (ws_size >= cls_bytes + q_bytes) {
        uint16_t* cls_bf = (uint16_t*)d_ws;
        uint16_t* q_bf   = (uint16_t*)((char*)d_ws + cls_bytes);
        prep_kernel<<<QBLK + CBLK, 256, 0, stream>>>(q, cls, M, q_bf, cls_bf);
        gemm_kernel<<<(N_Q / 256) * (N_CLS / 256), 512, 0, stream>>>(q_bf, cls_bf, out);
    } else {
        naive_kernel<<<(unsigned)(((size_t)N_Q * N_CLS) / 256), 256, 0, stream>>>(q, cls, M, out);
    }
}